// Round 7
// baseline (215.080 us; speedup 1.0000x reference)
//
#include <hip/hip_runtime.h>

#define D_ 160
#define H_ 192
#define W_ 160
#define HW_ (H_*W_)
#define V_ (D_*H_*W_)
#define NTOT (2*V_)

#define TW 32
#define TH 16
#define DC 20
#define NCHUNK (D_/DC)    // 8
#define RH 24             // TH + 8 halo
#define TWP 33            // 32 cols + 1 pad
#define NBLOCKS (5*12*NCHUNK*2)   // 960

// RTNE f32x2 -> packed bf16x2 (p0 high, p1 low) and back.
__device__ inline unsigned pack_bf2(float a, float b) {
  unsigned ua = __float_as_uint(a), ub = __float_as_uint(b);
  ua += 0x7fffu + ((ua >> 16) & 1u);
  ub += 0x7fffu + ((ub >> 16) & 1u);
  return (ua & 0xffff0000u) | (ub >> 16);
}
__device__ inline float2 unpack_bf2(unsigned u) {
  return make_float2(__uint_as_float(u & 0xffff0000u),
                     __uint_as_float(u << 16));
}

// ---------------------------------------------------------------------------
// Fused separable 9x9x9 box filter + NCC, NO input staging in LDS.
// Per step t (ring slot u = t mod 9 static via 9-unroll, no break — R5/R6
// lesson: any dynamic ring index or over-cap register demand => scratch):
//   C: H-dir 9-sums of ws (slice c0-6+t) + bf16 D-ring + emit   (t in [2,30))
//   sync1
//   B: global->reg 12-col window of slice c0-5+t, W-dir 9-sums  (t in [1,29))
//      (runs of 4, sliding), write ws
//   sync2
// LDS = ws only (15.8 KB). B's wave-overlapping global segments dedupe in L1;
// unique HBM traffic is the same as the staged version.
// ---------------------------------------------------------------------------
__global__ __launch_bounds__(256, 4) void ncc_fused(const float* __restrict__ I,
                                                    const float* __restrict__ J,
                                                    float* __restrict__ bsum) {
  __shared__ float4 ws4[RH][TWP];      // W-sums f0-3  12672 B
  __shared__ float  ws1[RH][TWP];      // W-sums f4     3168 B

  const int tid = threadIdx.x;
  const int w0 = blockIdx.x * TW;               // 5
  const int h0 = blockIdx.y * TH;               // 12
  const int c0 = (blockIdx.z % NCHUNK) * DC;    // 8 chunks
  const int batch = blockIdx.z / NCHUNK;        // 2

  const float* Ib = I + (size_t)batch * V_;
  const float* Jb = J + (size_t)batch * V_;

  // B mapping (tid < 192): 24 rows x 8 runs of 4
  const int br  = tid >> 3;
  const int bc  = (tid & 7) * 4;
  const int bh  = h0 - 4 + br;
  const bool b_hv = (unsigned)bh < (unsigned)H_;
  const size_t b_row = (size_t)(b_hv ? bh : 0) * W_;
  const int bw0 = w0 + bc - 4;        // quad-aligned window start

  // C mapping: col tx, output rows hb and hb+1
  const int tx = tid & 31;
  const int hb = (tid >> 5) * 2;

  unsigned ring[5][9];
  float sum0[5], sum1[5];
#pragma unroll
  for (int f = 0; f < 5; ++f) {
    sum0[f] = 0.f; sum1[f] = 0.f;
#pragma unroll
    for (int k = 0; k < 9; ++k) ring[f][k] = 0u;
  }

  float local = 0.f;

#pragma unroll 1
  for (int tb = 0; tb < 36; tb += 9) {
#pragma unroll
    for (int u = 0; u < 9; ++u) {
      const int t = tb + u;          // 0..35; phases self-guard (30..35 idle)

      // ---- C: H-dir 9-sums of ws + bf16 D-ring (static slot u) ----
      if (t >= 2 && t < DC + 10) {
        float v0 = 0.f, v1 = 0.f, v2 = 0.f, v3 = 0.f, v4 = 0.f;
        float4 k4; float k1v;
#pragma unroll
        for (int k = 0; k < 9; ++k) {
          const float4 a4 = ws4[hb + k][tx];
          const float  a1 = ws1[hb + k][tx];
          if (k == 0) { k4 = a4; k1v = a1; }
          v0 += a4.x; v1 += a4.y; v2 += a4.z; v3 += a4.w; v4 += a1;
        }
        const float4 t4 = ws4[hb + 9][tx];
        const float  t1 = ws1[hb + 9][tx];
        float hv0[5], hv1[5];
        hv0[0] = v0; hv0[1] = v1; hv0[2] = v2; hv0[3] = v3; hv0[4] = v4;
        hv1[0] = v0 + t4.x - k4.x;
        hv1[1] = v1 + t4.y - k4.y;
        hv1[2] = v2 + t4.z - k4.z;
        hv1[3] = v3 + t4.w - k4.w;
        hv1[4] = v4 + t1   - k1v;

#pragma unroll
        for (int f = 0; f < 5; ++f) {
          const float2 old = unpack_bf2(ring[f][u]);
          sum0[f] += hv0[f] - old.x;
          sum1[f] += hv1[f] - old.y;
          ring[f][u] = pack_bf2(hv0[f], hv1[f]);
        }

        if (t >= 10) {
          const float inv = 1.f / 729.f;
          const float cx0 = sum0[4] - sum0[0] * sum0[1] * inv;
          const float iv0 = sum0[2] - sum0[0] * sum0[0] * inv;
          const float jv0 = sum0[3] - sum0[1] * sum0[1] * inv;
          local += cx0 * cx0 * __builtin_amdgcn_rcpf(iv0 * jv0 + 1e-5f);
          const float cx1 = sum1[4] - sum1[0] * sum1[1] * inv;
          const float iv1 = sum1[2] - sum1[0] * sum1[0] * inv;
          const float jv1 = sum1[3] - sum1[1] * sum1[1] * inv;
          local += cx1 * cx1 * __builtin_amdgcn_rcpf(iv1 * jv1 + 1e-5f);
        }
      }

      __syncthreads();

      // ---- B: global 12-col window of slice c0-5+t -> W-dir 9-sums -> ws ----
      if (t >= 1 && t < DC + 9 && tid < 192) {
        const int s = c0 - 5 + t;
        const bool rv = (s >= 0) && (s < D_) && b_hv;
        const float* rowI = Ib + (size_t)(rv ? s : 0) * HW_ + b_row;
        const float* rowJ = Jb + (size_t)(rv ? s : 0) * HW_ + b_row;
        float ai[12], aj[12];
#pragma unroll
        for (int q = 0; q < 3; ++q) {
          const int col = bw0 + 4 * q;     // quad-aligned: fully in or out
          float4 qa = {0,0,0,0}, qb = {0,0,0,0};
          if (rv && col >= 0 && col < W_) {
            qa = *(const float4*)(rowI + col);
            qb = *(const float4*)(rowJ + col);
          }
          ai[4*q+0] = qa.x; ai[4*q+1] = qa.y; ai[4*q+2] = qa.z; ai[4*q+3] = qa.w;
          aj[4*q+0] = qb.x; aj[4*q+1] = qb.y; aj[4*q+2] = qb.z; aj[4*q+3] = qb.w;
        }
        float4* W4 = ws4[br];
        float*  W1 = ws1[br];
        float s0 = 0.f, s1 = 0.f, s2 = 0.f, s3 = 0.f, s4 = 0.f;
#pragma unroll
        for (int k = 0; k < 9; ++k) {
          const float a = ai[k], b = aj[k];
          s0 += a; s1 += b; s2 += a * a; s3 += b * b; s4 += a * b;
        }
        W4[bc] = make_float4(s0, s1, s2, s3);
        W1[bc] = s4;
#pragma unroll
        for (int m = 1; m < 4; ++m) {
          const float ea = ai[8 + m], eb = aj[8 + m];
          const float la = ai[m - 1], lb = aj[m - 1];
          s0 += ea - la;
          s1 += eb - lb;
          s2 += ea * ea - la * la;
          s3 += eb * eb - lb * lb;
          s4 += ea * eb - la * lb;
          W4[bc + m] = make_float4(s0, s1, s2, s3);
          W1[bc + m] = s4;
        }
      }

      __syncthreads();
    }
  }

  // ---- block reduction (reuse ws4 space) -> per-block partial ----
  float* red = (float*)&ws4[0][0];
  red[tid] = local;
  __syncthreads();
  for (int s2 = 128; s2 > 0; s2 >>= 1) {
    if (tid < s2) red[tid] += red[tid + s2];
    __syncthreads();
  }
  if (tid == 0) {
    const int bid = (blockIdx.z * 12 + blockIdx.y) * 5 + blockIdx.x;
    bsum[bid] = red[0];
  }
}

__global__ __launch_bounds__(256) void finalize_k(const float* __restrict__ bsum,
                                                  float* __restrict__ out) {
  __shared__ double red[256];
  double d = 0.0;
  for (int i = threadIdx.x; i < NBLOCKS; i += 256) d += (double)bsum[i];
  red[threadIdx.x] = d;
  __syncthreads();
  for (int s = 128; s > 0; s >>= 1) {
    if (threadIdx.x < s) red[threadIdx.x] += red[threadIdx.x + s];
    __syncthreads();
  }
  if (threadIdx.x == 0) out[0] = (float)(-red[0] / (double)NTOT);
}

extern "C" void kernel_launch(void* const* d_in, const int* in_sizes, int n_in,
                              void* d_out, int out_size, void* d_ws, size_t ws_size,
                              hipStream_t stream) {
  const float* I = (const float*)d_in[0];   // y_true
  const float* J = (const float*)d_in[1];   // y_pred
  float* out = (float*)d_out;
  float* bsum = (float*)d_ws;               // 960 floats

  dim3 grid(W_ / TW, H_ / TH, NCHUNK * 2);  // 5 x 12 x 16 = 960 blocks
  ncc_fused<<<grid, 256, 0, stream>>>(I, J, bsum);
  finalize_k<<<1, 256, 0, stream>>>(bsum, out);
}

// Round 8
// 198.401 us; speedup vs baseline: 1.0841x; 1.0841x over previous
//
#include <hip/hip_runtime.h>

#define D_ 160
#define H_ 192
#define W_ 160
#define HW_ (H_*W_)
#define V_ (D_*H_*W_)
#define NTOT (2*V_)

#define TW 32
#define TH 16
#define DC 20
#define NCHUNK (D_/DC)    // 8
#define RH 24             // TH + 8 halo
#define TWP 33            // ws stride pad (33%8==1 -> uniform quad-banks)
#define NBLOCKS (5*12*NCHUNK*2)   // 960

// 16B global->LDS DMA. LDS dest = wave-uniform base + lane*16 (m97/m104).
#define GLD16(gp, lp) \
  __builtin_amdgcn_global_load_lds( \
      (const __attribute__((address_space(1))) unsigned int*)(const void*)(gp), \
      (__attribute__((address_space(3))) unsigned int*)(void*)(lp), 16, 0, 0)

// RTNE f32x2 -> packed bf16x2 and back (validated R5/R6: absmax 0.0).
__device__ inline unsigned pack_bf2(float a, float b) {
  unsigned ua = __float_as_uint(a), ub = __float_as_uint(b);
  ua += 0x7fffu + ((ua >> 16) & 1u);
  ub += 0x7fffu + ((ub >> 16) & 1u);
  return (ua & 0xffff0000u) | (ub >> 16);
}
__device__ inline float2 unpack_bf2(unsigned u) {
  return make_float2(__uint_as_float(u & 0xffff0000u),
                     __uint_as_float(u << 16));
}

// ---------------------------------------------------------------------------
// Fused separable 9x9x9 box filter + NCC.
// Staging via global_load_lds DMA (no staging registers — R6/R7 lesson: any
// config whose unified reg demand exceeds the launch_bounds cap spills and
// loses; the DMA removes ~25 regs of staging state).
// Per step t (ring slot u = t mod 9 static via 9-unroll, no break):
//   stage: DMA slice s=c0-4+t -> sIJ[t&1]        (t in [0,28))
//   C: H-dir 9-sums of ws + bf16 D-ring + emit   (t in [2,30))
//   sync1
//   B: 6x ds_read_b128 12-col window from sIJ[(t+1)&1], W-dir 9-sums -> ws
//   sync2 (drains DMA vmcnt before next step's B reads the staged buffer)
// Boundary lanes are exec-masked; their LDS slots are pre-zeroed once and
// never written. d-OOB slices (wave-uniform) take a ds_write zero-fill path.
// ---------------------------------------------------------------------------
__global__ __launch_bounds__(256, 4) void ncc_fused(const float* __restrict__ I,
                                                    const float* __restrict__ J,
                                                    float* __restrict__ bsum) {
  __shared__ float4 sIJ[2][480];       // [buf][ I quads 0..239 | J quads 240..479 ]
  __shared__ float4 ws4[RH][TWP];      // W-sums f0-3  12672 B
  __shared__ float  ws1[RH][TWP];      // W-sums f4     3168 B

  const int tid = threadIdx.x;
  const int w0 = blockIdx.x * TW;               // 5
  const int h0 = blockIdx.y * TH;               // 12
  const int c0 = (blockIdx.z % NCHUNK) * DC;    // 8 chunks
  const int batch = blockIdx.z / NCHUNK;        // 2

  const float* Ib = I + (size_t)batch * V_;
  const float* Jb = J + (size_t)batch * V_;

  // Staging chunks g0=tid, g1=tid+256 of 480. chunk g: arr=g/240, rem=g%240,
  // row r=rem/10 (h=h0-4+r), quad q=rem%10 (col=w0-4+4q, quad-aligned).
  const int g0 = tid, g1 = tid + 256;
  const int a0 = g0 / 240, rem0 = g0 % 240;
  const int r0 = rem0 / 10, q0 = rem0 % 10;
  const int h0g = h0 - 4 + r0, c0g = w0 - 4 + 4 * q0;
  const bool ok0 = ((unsigned)h0g < (unsigned)H_) && ((unsigned)c0g < (unsigned)W_);
  const float* gb0 = (a0 ? Jb : Ib) + (ok0 ? ((size_t)h0g * W_ + c0g) : 0);

  const int a1 = (g1 / 240) & 1, rem1 = g1 % 240;
  const int r1 = rem1 / 10, q1 = rem1 % 10;
  const int h1g = h0 - 4 + r1, c1g = w0 - 4 + 4 * q1;
  const bool ok1 = (g1 < 480) && ((unsigned)h1g < (unsigned)H_) && ((unsigned)c1g < (unsigned)W_);
  const float* gb1 = (a1 ? Jb : Ib) + (ok1 ? ((size_t)h1g * W_ + c1g) : 0);

  // Wave-uniform LDS byte bases for the two DMA issues.
  const int wv  = tid >> 6;
  const int wb0 = wv * 1024;           // chunks [wv*64, wv*64+64)
  const int wb1 = 4096 + wv * 1024;    // chunks [256+wv*64, ...)

  // B mapping (tid < 192): 24 rows x 8 runs of 4
  const int br = tid >> 3;
  const int brun = tid & 7;
  const int bc = brun * 4;

  // C mapping: col tx, output rows hb, hb+1
  const int tx = tid & 31;
  const int hb = (tid >> 5) * 2;

  unsigned ring[5][9];
  float sum0[5], sum1[5];
#pragma unroll
  for (int f = 0; f < 5; ++f) {
    sum0[f] = 0.f; sum1[f] = 0.f;
#pragma unroll
    for (int k = 0; k < 9; ++k) ring[f][k] = 0u;
  }

  // Pre-zero both staging buffers (masked boundary slots stay zero forever).
  const float4 z4 = make_float4(0.f, 0.f, 0.f, 0.f);
  for (int i = tid; i < 960; i += 256) ((float4*)sIJ)[i] = z4;
  __syncthreads();

  float local = 0.f;

#pragma unroll 1
  for (int tb = 0; tb < 36; tb += 9) {
#pragma unroll
    for (int u = 0; u < 9; ++u) {
      const int t = tb + u;          // 0..35; phases self-guard (30..35 idle)

      // ---- stage: slice s = c0-4+t -> sIJ[t&1] via DMA ----
      if (t < DC + 8) {
        const int s = c0 - 4 + t;
        char* lbase = (char*)&sIJ[t & 1][0];
        if ((unsigned)s < (unsigned)D_) {
          const size_t so = (size_t)s * HW_;
          if (ok0) GLD16(gb0 + so, lbase + wb0);
          if (ok1) GLD16(gb1 + so, lbase + wb1);
        } else {
          ((float4*)lbase)[g0] = z4;
          if (g1 < 480) ((float4*)lbase)[g1] = z4;
        }
      }

      // ---- C: H-dir 9-sums of ws + bf16 D-ring (static slot u) ----
      if (t >= 2 && t < DC + 10) {
        float v0 = 0.f, v1 = 0.f, v2 = 0.f, v3 = 0.f, v4 = 0.f;
        float4 k4; float k1v;
#pragma unroll
        for (int k = 0; k < 9; ++k) {
          const float4 a4 = ws4[hb + k][tx];
          const float  a1f = ws1[hb + k][tx];
          if (k == 0) { k4 = a4; k1v = a1f; }
          v0 += a4.x; v1 += a4.y; v2 += a4.z; v3 += a4.w; v4 += a1f;
        }
        const float4 t4 = ws4[hb + 9][tx];
        const float  t1 = ws1[hb + 9][tx];
        float hv0[5], hv1[5];
        hv0[0] = v0; hv0[1] = v1; hv0[2] = v2; hv0[3] = v3; hv0[4] = v4;
        hv1[0] = v0 + t4.x - k4.x;
        hv1[1] = v1 + t4.y - k4.y;
        hv1[2] = v2 + t4.z - k4.z;
        hv1[3] = v3 + t4.w - k4.w;
        hv1[4] = v4 + t1   - k1v;

#pragma unroll
        for (int f = 0; f < 5; ++f) {
          const float2 old = unpack_bf2(ring[f][u]);
          sum0[f] += hv0[f] - old.x;
          sum1[f] += hv1[f] - old.y;
          ring[f][u] = pack_bf2(hv0[f], hv1[f]);
        }

        if (t >= 10) {
          const float inv = 1.f / 729.f;
          const float cx0 = sum0[4] - sum0[0] * sum0[1] * inv;
          const float iv0 = sum0[2] - sum0[0] * sum0[0] * inv;
          const float jv0 = sum0[3] - sum0[1] * sum0[1] * inv;
          local += cx0 * cx0 * __builtin_amdgcn_rcpf(iv0 * jv0 + 1e-5f);
          const float cx1 = sum1[4] - sum1[0] * sum1[1] * inv;
          const float iv1 = sum1[2] - sum1[0] * sum1[0] * inv;
          const float jv1 = sum1[3] - sum1[1] * sum1[1] * inv;
          local += cx1 * cx1 * __builtin_amdgcn_rcpf(iv1 * jv1 + 1e-5f);
        }
      }

      __syncthreads();

      // ---- B: W-dir 9-sums from sIJ[(t+1)&1] (6x ds_read_b128) -> ws ----
      if (t >= 1 && t < DC + 9 && tid < 192) {
        const float4* SI = &sIJ[(t + 1) & 1][br * 10 + brun];
        const float4* SJ = SI + 240;
        const float4 A0 = SI[0], A1 = SI[1], A2 = SI[2];
        const float4 B0 = SJ[0], B1 = SJ[1], B2 = SJ[2];
        const float ai[12] = {A0.x,A0.y,A0.z,A0.w, A1.x,A1.y,A1.z,A1.w,
                              A2.x,A2.y,A2.z,A2.w};
        const float aj[12] = {B0.x,B0.y,B0.z,B0.w, B1.x,B1.y,B1.z,B1.w,
                              B2.x,B2.y,B2.z,B2.w};
        float4* W4 = ws4[br];
        float*  W1 = ws1[br];
        float s0 = 0.f, s1 = 0.f, s2 = 0.f, s3 = 0.f, s4 = 0.f;
#pragma unroll
        for (int k = 0; k < 9; ++k) {
          const float a = ai[k], b = aj[k];
          s0 += a; s1 += b; s2 += a * a; s3 += b * b; s4 += a * b;
        }
        W4[bc] = make_float4(s0, s1, s2, s3);
        W1[bc] = s4;
#pragma unroll
        for (int m = 1; m < 4; ++m) {
          const float ea = ai[8 + m], eb = aj[8 + m];
          const float la = ai[m - 1], lb = aj[m - 1];
          s0 += ea - la;
          s1 += eb - lb;
          s2 += ea * ea - la * la;
          s3 += eb * eb - lb * lb;
          s4 += ea * eb - la * lb;
          W4[bc + m] = make_float4(s0, s1, s2, s3);
          W1[bc + m] = s4;
        }
      }

      __syncthreads();
    }
  }

  // ---- block reduction (reuse ws4 space) -> per-block partial ----
  float* red = (float*)&ws4[0][0];
  red[tid] = local;
  __syncthreads();
  for (int s2 = 128; s2 > 0; s2 >>= 1) {
    if (tid < s2) red[tid] += red[tid + s2];
    __syncthreads();
  }
  if (tid == 0) {
    const int bid = (blockIdx.z * 12 + blockIdx.y) * 5 + blockIdx.x;
    bsum[bid] = red[0];
  }
}

__global__ __launch_bounds__(256) void finalize_k(const float* __restrict__ bsum,
                                                  float* __restrict__ out) {
  __shared__ double red[256];
  double d = 0.0;
  for (int i = threadIdx.x; i < NBLOCKS; i += 256) d += (double)bsum[i];
  red[threadIdx.x] = d;
  __syncthreads();
  for (int s = 128; s > 0; s >>= 1) {
    if (threadIdx.x < s) red[threadIdx.x] += red[threadIdx.x + s];
    __syncthreads();
  }
  if (threadIdx.x == 0) out[0] = (float)(-red[0] / (double)NTOT);
}

extern "C" void kernel_launch(void* const* d_in, const int* in_sizes, int n_in,
                              void* d_out, int out_size, void* d_ws, size_t ws_size,
                              hipStream_t stream) {
  const float* I = (const float*)d_in[0];   // y_true
  const float* J = (const float*)d_in[1];   // y_pred
  float* out = (float*)d_out;
  float* bsum = (float*)d_ws;               // 960 floats

  dim3 grid(W_ / TW, H_ / TH, NCHUNK * 2);  // 5 x 12 x 16 = 960 blocks
  ncc_fused<<<grid, 256, 0, stream>>>(I, J, bsum);
  finalize_k<<<1, 256, 0, stream>>>(bsum, out);
}

// Round 9
// 164.066 us; speedup vs baseline: 1.3109x; 1.2093x over previous
//
#include <hip/hip_runtime.h>

#define D_ 160
#define H_ 192
#define W_ 160
#define HW_ (H_*W_)
#define V_ (D_*H_*W_)
#define NTOT (2*V_)

#define TW 32
#define TH 16
#define DC 20
#define NCHUNK (D_/DC)    // 8
#define RH 24             // TH + 8 halo
#define TWP 33            // ws stride pad (33%8==1 -> uniform quad-banks)
#define NBLOCKS (5*12*NCHUNK*2)   // 960

// 16B global->LDS DMA. LDS dest = wave-uniform base + lane*16 (m97/m104).
#define GLD16(gp, lp) \
  __builtin_amdgcn_global_load_lds( \
      (const __attribute__((address_space(1))) unsigned int*)(const void*)(gp), \
      (__attribute__((address_space(3))) unsigned int*)(void*)(lp), 16, 0, 0)

// RTNE f32x2 -> packed bf16x2 and back (validated R5/R6/R8: absmax 0.0).
__device__ inline unsigned pack_bf2(float a, float b) {
  unsigned ua = __float_as_uint(a), ub = __float_as_uint(b);
  ua += 0x7fffu + ((ua >> 16) & 1u);
  ub += 0x7fffu + ((ub >> 16) & 1u);
  return (ua & 0xffff0000u) | (ub >> 16);
}
__device__ inline float2 unpack_bf2(unsigned u) {
  return make_float2(__uint_as_float(u & 0xffff0000u),
                     __uint_as_float(u << 16));
}

// ---------------------------------------------------------------------------
// Fused separable 9x9x9 box filter + NCC.
// launch_bounds(256,3): cap 170 unified regs. R5-R8 lesson: this kernel's
// true demand is ~150; every 128-cap config spilled 30-150 MB of scratch and
// lost. (256,3) configs never spill.
// Structure (per step t; ring slot u = t mod 9 static via 9-unroll, no break):
//   stage: DMA slice s=c0-4+t -> sIJ[t&1]        (t in [0,28))
//   C: H-dir 9-sums of ws + bf16 D-ring + emit   (t in [2,30))
//   sync1
//   B: 6x ds_read_b128 12-col window from sIJ[(t+1)&1], W-dir 9-sums -> ws
//   sync2 (drains DMA vmcnt before next step's B reads the staged buffer)
// Boundary lanes exec-masked off the DMA; their slots pre-zeroed once.
// ---------------------------------------------------------------------------
__global__ __launch_bounds__(256, 3) void ncc_fused(const float* __restrict__ I,
                                                    const float* __restrict__ J,
                                                    float* __restrict__ bsum) {
  __shared__ float4 sIJ[2][480];       // [buf][ I quads 0..239 | J quads 240..479 ]
  __shared__ float4 ws4[RH][TWP];      // W-sums f0-3  12672 B
  __shared__ float  ws1[RH][TWP];      // W-sums f4     3168 B

  const int tid = threadIdx.x;
  const int w0 = blockIdx.x * TW;               // 5
  const int h0 = blockIdx.y * TH;               // 12
  const int c0 = (blockIdx.z % NCHUNK) * DC;    // 8 chunks
  const int batch = blockIdx.z / NCHUNK;        // 2

  const float* Ib = I + (size_t)batch * V_;
  const float* Jb = J + (size_t)batch * V_;

  // Staging chunks g0=tid, g1=tid+256 of 480. chunk g: arr=g/240, rem=g%240,
  // row r=rem/10 (h=h0-4+r), quad q=rem%10 (col=w0-4+4q, quad-aligned).
  const int g0 = tid, g1 = tid + 256;
  const int a0 = g0 / 240, rem0 = g0 % 240;
  const int r0 = rem0 / 10, q0 = rem0 % 10;
  const int h0g = h0 - 4 + r0, c0g = w0 - 4 + 4 * q0;
  const bool ok0 = ((unsigned)h0g < (unsigned)H_) && ((unsigned)c0g < (unsigned)W_);
  const float* gb0 = (a0 ? Jb : Ib) + (ok0 ? ((size_t)h0g * W_ + c0g) : 0);

  const int a1 = (g1 / 240) & 1, rem1 = g1 % 240;
  const int r1 = rem1 / 10, q1 = rem1 % 10;
  const int h1g = h0 - 4 + r1, c1g = w0 - 4 + 4 * q1;
  const bool ok1 = (g1 < 480) && ((unsigned)h1g < (unsigned)H_) && ((unsigned)c1g < (unsigned)W_);
  const float* gb1 = (a1 ? Jb : Ib) + (ok1 ? ((size_t)h1g * W_ + c1g) : 0);

  // Wave-uniform LDS byte bases for the two DMA issues.
  const int wv  = tid >> 6;
  const int wb0 = wv * 1024;           // chunks [wv*64, wv*64+64)
  const int wb1 = 4096 + wv * 1024;    // chunks [256+wv*64, ...)

  // B mapping (tid < 192): 24 rows x 8 runs of 4
  const int br = tid >> 3;
  const int brun = tid & 7;
  const int bc = brun * 4;

  // C mapping: col tx, output rows hb, hb+1
  const int tx = tid & 31;
  const int hb = (tid >> 5) * 2;

  unsigned ring[5][9];
  float sum0[5], sum1[5];
#pragma unroll
  for (int f = 0; f < 5; ++f) {
    sum0[f] = 0.f; sum1[f] = 0.f;
#pragma unroll
    for (int k = 0; k < 9; ++k) ring[f][k] = 0u;
  }

  // Pre-zero both staging buffers (masked boundary slots stay zero forever).
  const float4 z4 = make_float4(0.f, 0.f, 0.f, 0.f);
  for (int i = tid; i < 960; i += 256) ((float4*)sIJ)[i] = z4;
  __syncthreads();

  float local = 0.f;

#pragma unroll 1
  for (int tb = 0; tb < 36; tb += 9) {
#pragma unroll
    for (int u = 0; u < 9; ++u) {
      const int t = tb + u;          // 0..35; phases self-guard (30..35 idle)

      // ---- stage: slice s = c0-4+t -> sIJ[t&1] via DMA ----
      if (t < DC + 8) {
        const int s = c0 - 4 + t;
        char* lbase = (char*)&sIJ[t & 1][0];
        if ((unsigned)s < (unsigned)D_) {
          const size_t so = (size_t)s * HW_;
          if (ok0) GLD16(gb0 + so, lbase + wb0);
          if (ok1) GLD16(gb1 + so, lbase + wb1);
        } else {
          ((float4*)lbase)[g0] = z4;
          if (g1 < 480) ((float4*)lbase)[g1] = z4;
        }
      }

      // ---- C: H-dir 9-sums of ws + bf16 D-ring (static slot u) ----
      if (t >= 2 && t < DC + 10) {
        float v0 = 0.f, v1 = 0.f, v2 = 0.f, v3 = 0.f, v4 = 0.f;
        float4 k4; float k1v;
#pragma unroll
        for (int k = 0; k < 9; ++k) {
          const float4 a4 = ws4[hb + k][tx];
          const float  a1f = ws1[hb + k][tx];
          if (k == 0) { k4 = a4; k1v = a1f; }
          v0 += a4.x; v1 += a4.y; v2 += a4.z; v3 += a4.w; v4 += a1f;
        }
        const float4 t4 = ws4[hb + 9][tx];
        const float  t1 = ws1[hb + 9][tx];
        float hv0[5], hv1[5];
        hv0[0] = v0; hv0[1] = v1; hv0[2] = v2; hv0[3] = v3; hv0[4] = v4;
        hv1[0] = v0 + t4.x - k4.x;
        hv1[1] = v1 + t4.y - k4.y;
        hv1[2] = v2 + t4.z - k4.z;
        hv1[3] = v3 + t4.w - k4.w;
        hv1[4] = v4 + t1   - k1v;

#pragma unroll
        for (int f = 0; f < 5; ++f) {
          const float2 old = unpack_bf2(ring[f][u]);
          sum0[f] += hv0[f] - old.x;
          sum1[f] += hv1[f] - old.y;
          ring[f][u] = pack_bf2(hv0[f], hv1[f]);
        }

        if (t >= 10) {
          const float inv = 1.f / 729.f;
          const float cx0 = sum0[4] - sum0[0] * sum0[1] * inv;
          const float iv0 = sum0[2] - sum0[0] * sum0[0] * inv;
          const float jv0 = sum0[3] - sum0[1] * sum0[1] * inv;
          local += cx0 * cx0 * __builtin_amdgcn_rcpf(iv0 * jv0 + 1e-5f);
          const float cx1 = sum1[4] - sum1[0] * sum1[1] * inv;
          const float iv1 = sum1[2] - sum1[0] * sum1[0] * inv;
          const float jv1 = sum1[3] - sum1[1] * sum1[1] * inv;
          local += cx1 * cx1 * __builtin_amdgcn_rcpf(iv1 * jv1 + 1e-5f);
        }
      }

      __syncthreads();

      // ---- B: W-dir 9-sums from sIJ[(t+1)&1] (6x ds_read_b128) -> ws ----
      if (t >= 1 && t < DC + 9 && tid < 192) {
        const float4* SI = &sIJ[(t + 1) & 1][br * 10 + brun];
        const float4* SJ = SI + 240;
        const float4 A0 = SI[0], A1 = SI[1], A2 = SI[2];
        const float4 B0 = SJ[0], B1 = SJ[1], B2 = SJ[2];
        const float ai[12] = {A0.x,A0.y,A0.z,A0.w, A1.x,A1.y,A1.z,A1.w,
                              A2.x,A2.y,A2.z,A2.w};
        const float aj[12] = {B0.x,B0.y,B0.z,B0.w, B1.x,B1.y,B1.z,B1.w,
                              B2.x,B2.y,B2.z,B2.w};
        float4* W4 = ws4[br];
        float*  W1 = ws1[br];
        float s0 = 0.f, s1 = 0.f, s2 = 0.f, s3 = 0.f, s4 = 0.f;
#pragma unroll
        for (int k = 0; k < 9; ++k) {
          const float a = ai[k], b = aj[k];
          s0 += a; s1 += b; s2 += a * a; s3 += b * b; s4 += a * b;
        }
        W4[bc] = make_float4(s0, s1, s2, s3);
        W1[bc] = s4;
#pragma unroll
        for (int m = 1; m < 4; ++m) {
          const float ea = ai[8 + m], eb = aj[8 + m];
          const float la = ai[m - 1], lb = aj[m - 1];
          s0 += ea - la;
          s1 += eb - lb;
          s2 += ea * ea - la * la;
          s3 += eb * eb - lb * lb;
          s4 += ea * eb - la * lb;
          W4[bc + m] = make_float4(s0, s1, s2, s3);
          W1[bc + m] = s4;
        }
      }

      __syncthreads();
    }
  }

  // ---- block reduction (reuse ws4 space) -> per-block partial ----
  float* red = (float*)&ws4[0][0];
  red[tid] = local;
  __syncthreads();
  for (int s2 = 128; s2 > 0; s2 >>= 1) {
    if (tid < s2) red[tid] += red[tid + s2];
    __syncthreads();
  }
  if (tid == 0) {
    const int bid = (blockIdx.z * 12 + blockIdx.y) * 5 + blockIdx.x;
    bsum[bid] = red[0];
  }
}

__global__ __launch_bounds__(256) void finalize_k(const float* __restrict__ bsum,
                                                  float* __restrict__ out) {
  __shared__ double red[256];
  double d = 0.0;
  for (int i = threadIdx.x; i < NBLOCKS; i += 256) d += (double)bsum[i];
  red[threadIdx.x] = d;
  __syncthreads();
  for (int s = 128; s > 0; s >>= 1) {
    if (threadIdx.x < s) red[threadIdx.x] += red[threadIdx.x + s];
    __syncthreads();
  }
  if (threadIdx.x == 0) out[0] = (float)(-red[0] / (double)NTOT);
}

extern "C" void kernel_launch(void* const* d_in, const int* in_sizes, int n_in,
                              void* d_out, int out_size, void* d_ws, size_t ws_size,
                              hipStream_t stream) {
  const float* I = (const float*)d_in[0];   // y_true
  const float* J = (const float*)d_in[1];   // y_pred
  float* out = (float*)d_out;
  float* bsum = (float*)d_ws;               // 960 floats

  dim3 grid(W_ / TW, H_ / TH, NCHUNK * 2);  // 5 x 12 x 16 = 960 blocks
  ncc_fused<<<grid, 256, 0, stream>>>(I, J, bsum);
  finalize_k<<<1, 256, 0, stream>>>(bsum, out);
}